// Round 1
// baseline (285.016 us; speedup 1.0000x reference)
//
#include <hip/hip_runtime.h>

// 13-branch fused Conv3d(2->13, k=5, SAME) + bias + clip(0,100), fp32 direct.
// x: [16][2][64][64][64]  W: [13][2][5][5][5]  b: [13]  out: [16][13][64][64][64]

#define BB   16
#define CINC 2
#define DDIM 64
#define COUT 13
#define KK   5
#define PAD  2

#define ZT 2          // z-tile per block
#define YT 4          // y-tile per block
#define LZ (ZT + 4)   // 6 staged z planes
#define LY (YT + 4)   // 8 staged y rows
#define LX 68         // 64 + 2*2 halo

__global__ __launch_bounds__(256, 4)
void conv13_kernel(const float* __restrict__ X,
                   const float* __restrict__ W,
                   const float* __restrict__ Bv,
                   float* __restrict__ O) {
    __shared__ float lin[CINC][LZ][LY][LX];   // 6528 floats = 26.1 KB

    const int yt = blockIdx.x;   // 0..15
    const int zt = blockIdx.y;   // 0..31
    const int b  = blockIdx.z;   // 0..15
    const int z0 = zt * ZT;
    const int y0 = yt * YT;
    const int tid = threadIdx.x;

    // ---- stage input tile (zero-padded halo) ----
    const int TOT = CINC * LZ * LY * LX;   // 6528
    for (int i = tid; i < TOT; i += 256) {
        int ci = i / (LZ * LY * LX);
        int r  = i % (LZ * LY * LX);
        int zz = r / (LY * LX);
        int r2 = r % (LY * LX);
        int yy = r2 / LX;
        int xl = r2 % LX;
        int gz = z0 + zz - PAD;
        int gy = y0 + yy - PAD;
        int gx = xl - PAD;
        float v = 0.0f;
        if ((unsigned)gz < DDIM && (unsigned)gy < DDIM && (unsigned)gx < DDIM)
            v = X[(((size_t)(b * CINC + ci) * DDIM + gz) * DDIM + gy) * DDIM + gx];
        ((float*)lin)[i] = v;
    }
    __syncthreads();

    // ---- compute: each thread = (tz, ty, xx) covers x in {xx, xx+32}, all 13 couts ----
    const int tz = tid >> 7;          // 0..1
    const int ty = (tid >> 5) & 3;    // 0..3
    const int xx = tid & 31;          // 0..31

    float acc[COUT][2];
    #pragma unroll
    for (int co = 0; co < COUT; ++co) {
        float bb = Bv[co];            // uniform -> s_load
        acc[co][0] = bb;
        acc[co][1] = bb;
    }

    for (int ci = 0; ci < CINC; ++ci) {
        for (int dz = 0; dz < KK; ++dz) {
            #pragma unroll
            for (int dy = 0; dy < KK; ++dy) {
                const float* row = &lin[ci][tz + dz][ty + dy][0];
                float xa[KK], xb[KK];
                #pragma unroll
                for (int d = 0; d < KK; ++d) {
                    xa[d] = row[xx + d];
                    xb[d] = row[xx + 32 + d];
                }
                // weights: uniform indices -> scalar loads (SGPR operands in FMA)
                const float* wr = W + (ci * 25 + dz * 5 + dy) * 5;
                #pragma unroll
                for (int co = 0; co < COUT; ++co) {
                    #pragma unroll
                    for (int d = 0; d < KK; ++d) {
                        float w = wr[co * (CINC * 125) + d];
                        acc[co][0] = fmaf(w, xa[d], acc[co][0]);
                        acc[co][1] = fmaf(w, xb[d], acc[co][1]);
                    }
                }
            }
        }
    }

    // ---- epilogue: clip + store ----
    const int oz = z0 + tz;
    const int oy = y0 + ty;
    #pragma unroll
    for (int co = 0; co < COUT; ++co) {
        float v0 = fminf(fmaxf(acc[co][0], 0.0f), 100.0f);
        float v1 = fminf(fmaxf(acc[co][1], 0.0f), 100.0f);
        size_t base = (((size_t)(b * COUT + co) * DDIM + oz) * DDIM + oy) * DDIM;
        O[base + xx]      = v0;
        O[base + xx + 32] = v1;
    }
}

extern "C" void kernel_launch(void* const* d_in, const int* in_sizes, int n_in,
                              void* d_out, int out_size, void* d_ws, size_t ws_size,
                              hipStream_t stream) {
    const float* X  = (const float*)d_in[0];
    const float* W  = (const float*)d_in[1];
    const float* Bv = (const float*)d_in[2];
    float* O = (float*)d_out;

    dim3 grid(DDIM / YT, DDIM / ZT, BB);   // (16, 32, 16) = 8192 blocks
    conv13_kernel<<<grid, 256, 0, stream>>>(X, W, Bv, O);
}

// Round 2
// 160.999 us; speedup vs baseline: 1.7703x; 1.7703x over previous
//
#include <hip/hip_runtime.h>

// 13-branch fused Conv3d(2->13, k=5, SAME) + bias + clip(0,100)
// bf16 MFMA implicit GEMM: D[m=cout][n=x] += sum_k W[m][k] * im2col[k][n]
// k-slot (kstep s, lane-group g, elem j): row r=4s+g -> (ci,dz,dy), dx=j (j<5)
// x: [16][2][64][64][64] f32, W: [13][2][5][5][5] f32, b: [13], out: [16][13][64][64][64] f32

typedef __attribute__((ext_vector_type(8))) short bf16x8;
typedef __attribute__((ext_vector_type(4))) float f32x4;

#define ZB 2
#define YB 8
#define ZR 6              // ZB + 4 halo
#define YR 12             // YB + 4 halo
#define NROWS (2*ZR*YR)   // 144 rows (ci,z',y')
#define PITCH 72          // u32 words per row: 36 even-pair + 36 odd-pair
#define NSTEP 13          // ceil(50 rows / 4 groups)

__device__ __forceinline__ unsigned f2bf(float f) {
    unsigned u = __builtin_bit_cast(unsigned, f);
    return (u + 0x7FFFu + ((u >> 16) & 1u)) >> 16;   // RNE bf16
}

__global__ __launch_bounds__(256, 3)
void conv13_mfma(const float* __restrict__ X,
                 const float* __restrict__ W,
                 const float* __restrict__ Bv,
                 float* __restrict__ O) {
    __shared__ unsigned lds[NROWS * PITCH];   // 41472 B

    const int tid = threadIdx.x;
    const int l   = tid & 63;
    const int wid = tid >> 6;          // 4 waves split x
    const int g   = l >> 4;
    const int lx  = l & 15;
    const int yt = blockIdx.x, zt = blockIdx.y, b = blockIdx.z;

    // ---- phase 0: build weight A-fragments in LDS: [s][lane][t] dwords ----
    for (int idx = tid; idx < NSTEP * 256; idx += 256) {
        int s = idx >> 8, rem = idx & 255;
        int lane = rem >> 2, t = rem & 3;
        int gg = lane >> 4, co = lane & 15;
        int r = 4 * s + gg;
        unsigned w0 = 0, w1 = 0;
        if (co < 13 && r < 50) {
            int ci = r / 25, r2 = r % 25;
            int dz = r2 / 5, dy = r2 % 5;
            const float* wr = W + ((((co * 2 + ci) * 5 + dz) * 5 + dy) * 5);
            int j0 = 2 * t, j1 = j0 + 1;
            if (j0 <= 4) w0 = f2bf(wr[j0]);
            if (j1 <= 4) w1 = f2bf(wr[j1]);
        }
        lds[idx] = w0 | (w1 << 16);
    }
    __syncthreads();

    bf16x8 wfrag[NSTEP];
    #pragma unroll
    for (int s = 0; s < NSTEP; ++s) {
        union { unsigned u[4]; bf16x8 v; } tmp;
        const unsigned* p = &lds[s * 256 + l * 4];
        tmp.u[0] = p[0]; tmp.u[1] = p[1]; tmp.u[2] = p[2]; tmp.u[3] = p[3];
        wfrag[s] = tmp.v;
    }

    // bias -> acc init (D row m = cout = 4g+v)
    float bv[4];
    #pragma unroll
    for (int v = 0; v < 4; ++v) {
        int co = 4 * g + v;
        bv[v] = (co < 13) ? Bv[co] : 0.0f;
    }

    // per-lane row-offset constants (bytes) for kstep s: row r = 4s+g
    int laneConst[NSTEP];
    #pragma unroll
    for (int s = 0; s < NSTEP; ++s) {
        int r = 4 * s + g; if (r > 49) r = 49;      // dummy (weights are 0)
        int ci = r / 25, r2 = r % 25;
        int dz = r2 / 5, dy = r2 % 5;
        laneConst[s] = ((ci * ZR + dz) * YR + dy) * (PITCH * 4);
    }
    const int e = wid * 16 + lx;                     // output x = window base
    const int xbyte = (e >> 1) * 4 + (e & 1) * 144;  // even/odd copy select

    __syncthreads();

    // ---- phase 1: stage X tile rows as even/odd bf16-pair copies ----
    // even[w] = (u=2w, 2w+1), odd[w] = (u=2w+1, 2w+2), value(u) = X[x = u-2]
    for (int idx = tid; idx < NROWS * 36; idx += 256) {
        int row = idx / 36, w = idx % 36;
        int ci = row / (ZR * YR);
        int rz = (row % (ZR * YR)) / YR;
        int ry = row % YR;
        int zi = zt * ZB + rz - 2;
        int yi = yt * YB + ry - 2;
        float v0 = 0.f, v1 = 0.f, v2 = 0.f;
        if ((unsigned)zi < 64u && (unsigned)yi < 64u) {
            const float* src = X + ((((size_t)b * 2 + ci) * 64 + zi) * 64 + yi) * 64;
            int x0i = 2 * w - 2;
            if ((unsigned)x0i < 64u)       v0 = src[x0i];
            if ((unsigned)(x0i + 1) < 64u) v1 = src[x0i + 1];
            if ((unsigned)(x0i + 2) < 64u) v2 = src[x0i + 2];
        }
        unsigned h0 = f2bf(v0), h1 = f2bf(v1), h2 = f2bf(v2);
        lds[row * PITCH + w]      = h0 | (h1 << 16);
        lds[row * PITCH + 36 + w] = h1 | (h2 << 16);
    }
    __syncthreads();

    // ---- phase 2: MFMA over ZB*YB output tiles ----
    for (int zz = 0; zz < ZB; ++zz) {
        for (int yy = 0; yy < YB; ++yy) {
            const int tileOff = (zz * YR + yy) * (PITCH * 4);
            f32x4 acc = { bv[0], bv[1], bv[2], bv[3] };
            #pragma unroll
            for (int s = 0; s < NSTEP; ++s) {
                const unsigned* p = (const unsigned*)((const char*)lds +
                                    (laneConst[s] + tileOff + xbyte));
                union { unsigned u[4]; bf16x8 v; } bb;
                bb.u[0] = p[0]; bb.u[1] = p[1]; bb.u[2] = p[2]; bb.u[3] = p[3];
                acc = __builtin_amdgcn_mfma_f32_16x16x32_bf16(wfrag[s], bb.v, acc, 0, 0, 0);
            }
            const int zi = zt * ZB + zz, yi = yt * YB + yy;
            float* dst = O + (((size_t)b * 13 * 64 + zi) * 64 + yi) * 64 + e;
            #pragma unroll
            for (int v = 0; v < 4; ++v) {
                int co = 4 * g + v;
                if (co < 13) {
                    float val = fminf(fmaxf(acc[v], 0.0f), 100.0f);
                    dst[(size_t)co * 262144] = val;
                }
            }
        }
    }
}

extern "C" void kernel_launch(void* const* d_in, const int* in_sizes, int n_in,
                              void* d_out, int out_size, void* d_ws, size_t ws_size,
                              hipStream_t stream) {
    const float* X  = (const float*)d_in[0];
    const float* W  = (const float*)d_in[1];
    const float* Bv = (const float*)d_in[2];
    float* O = (float*)d_out;

    dim3 grid(64 / YB, 64 / ZB, 16);   // (8, 32, 16) = 4096 blocks
    conv13_mfma<<<grid, 256, 0, stream>>>(X, W, Bv, O);
}

// Round 3
// 98.932 us; speedup vs baseline: 2.8809x; 1.6274x over previous
//
#include <hip/hip_runtime.h>

// 13-branch fused Conv3d(2->13, k=5, SAME) + bias + clip(0,100)
// bf16 MFMA implicit GEMM with weight-shift reuse:
//   D[m=cout][n] (16x16x32): B-fragment lane n holds in[4n-2 .. 4n+5] (8 bf16, 16B).
//   A_sh[j] = w[j-sh] (sh=0..3) -> same B serves outputs x = 4n+sh.
//   k-slot (group g, elem j): row (ci,dz,dy) = 4s+g, j = window element.
// x: [16][2][64][64][64] f32, W: [13][2][5][5][5] f32, b: [13], out: [16][13][64][64][64] f32

typedef __attribute__((ext_vector_type(8))) short bf16x8;
typedef __attribute__((ext_vector_type(4))) float f32x4;

#define ZB 2
#define YB 8
#define ZR 6               // ZB + 4
#define YR 12              // YB + 4
#define NROWS 144          // 2 * ZR * YR
#define UPITCH 72          // bf16 elements per row (68 used: x = -2..65)
#define ROWB 144           // bytes per row

__device__ __forceinline__ unsigned f2bf(float f) {
    unsigned u = __builtin_bit_cast(unsigned, f);
    return (u + 0x7FFFu + ((u >> 16) & 1u)) >> 16;   // RNE bf16
}

__global__ __launch_bounds__(256, 2)
void conv13_mfma_shift(const float* __restrict__ X,
                       const float* __restrict__ W,
                       const float* __restrict__ Bv,
                       float* __restrict__ O) {
    __shared__ unsigned short lds[NROWS * UPITCH];   // 20736 B

    const int tid = threadIdx.x;
    const int l   = tid & 63;
    const int wid = tid >> 6;
    const int g   = l >> 4;
    const int lx  = l & 15;
    const int yt = blockIdx.x, zt = blockIdx.y, b = blockIdx.z;

    // ---- A: weight fragments in registers. lane: m=cout=lx, k-row = 4s+g ----
    unsigned wf[13][4];
    int rowConst[13];                 // per-lane LDS byte offset of k-row (at tile origin)
    #pragma unroll
    for (int s = 0; s < 13; ++s) {
        int r  = 4 * s + g;
        int rc = (r < 50) ? r : 49;   // dummy row (weights forced 0)
        int ci = rc / 25, r2 = rc % 25, dz = r2 / 5, dy = r2 % 5;
        rowConst[s] = (ci * (ZR * YR) + dz * YR + dy) * ROWB;
        float w0 = 0.f, w1 = 0.f, w2 = 0.f, w3 = 0.f, w4 = 0.f;
        if (lx < 13 && r < 50) {
            const float* wr = W + ((lx * 2 + ci) * 25 + dz * 5 + dy) * 5;
            w0 = wr[0]; w1 = wr[1]; w2 = wr[2]; w3 = wr[3]; w4 = wr[4];
        }
        wf[s][0] = f2bf(w0) | (f2bf(w1) << 16);
        wf[s][1] = f2bf(w2) | (f2bf(w3) << 16);
        wf[s][2] = f2bf(w4);
        wf[s][3] = 0u;
    }

    // ---- stage X tile rows as bf16 (zero-padded), 8B chunks ----
    const int gz0 = zt * ZB - 2, gy0 = yt * YB - 2;
    for (int idx = tid; idx < NROWS * 18; idx += 256) {
        int row = idx / 18, q = idx % 18;        // q: 8-byte chunk (4 elems)
        int ci = row / (ZR * YR);
        int rz = (row / YR) % ZR;
        int ry = row % YR;
        int zi = gz0 + rz, yi = gy0 + ry;
        float v0 = 0.f, v1 = 0.f, v2 = 0.f, v3 = 0.f;
        if ((unsigned)zi < 64u && (unsigned)yi < 64u) {
            const float* src = X + ((((size_t)b * 2 + ci) * 64 + zi) * 64 + yi) * 64;
            int x0 = 4 * q - 2;                  // element u -> x = u - 2
            if ((unsigned)(x0 + 0) < 64u) v0 = src[x0 + 0];
            if ((unsigned)(x0 + 1) < 64u) v1 = src[x0 + 1];
            if ((unsigned)(x0 + 2) < 64u) v2 = src[x0 + 2];
            if ((unsigned)(x0 + 3) < 64u) v3 = src[x0 + 3];
        }
        unsigned* lp = (unsigned*)&lds[row * UPITCH + 4 * q];
        lp[0] = f2bf(v0) | (f2bf(v1) << 16);
        lp[1] = f2bf(v2) | (f2bf(v3) << 16);
    }

    // ---- per-wave tiles: 4 (z,y) rows each ----
    int tileOff[4], ozv[4], oyv[4];
    #pragma unroll
    for (int i = 0; i < 4; ++i) {
        int t = wid * 4 + i, zz = t >> 3, yy = t & 7;
        tileOff[i] = (zz * YR + yy) * ROWB;
        ozv[i] = zt * ZB + zz;
        oyv[i] = yt * YB + yy;
    }

    float bvv[4];
    #pragma unroll
    for (int v = 0; v < 4; ++v) {
        int co = 4 * g + v;
        bvv[v] = (co < 13) ? Bv[co] : 0.0f;
    }

    f32x4 acc[4][4];                  // [tile][shift]
    #pragma unroll
    for (int i = 0; i < 4; ++i)
        #pragma unroll
        for (int sh = 0; sh < 4; ++sh)
            acc[i][sh] = (f32x4){ bvv[0], bvv[1], bvv[2], bvv[3] };

    __syncthreads();

    // ---- main loop: 13 k-steps x (1 B-read set + 4 weight shifts x 4 tiles) ----
    #pragma unroll
    for (int s = 0; s < 13; ++s) {
        bf16x8 bb[4];
        #pragma unroll
        for (int i = 0; i < 4; ++i) {
            const char* p = (const char*)lds + (rowConst[s] + tileOff[i] + 8 * lx);
            uint2 lo = *(const uint2*)p;
            uint2 hi = *(const uint2*)(p + 8);
            union { unsigned u[4]; bf16x8 v; } tmp;
            tmp.u[0] = lo.x; tmp.u[1] = lo.y; tmp.u[2] = hi.x; tmp.u[3] = hi.y;
            bb[i] = tmp.v;
        }
        unsigned a0 = wf[s][0], a1 = wf[s][1], a2 = wf[s][2], a3 = wf[s][3];
        #pragma unroll
        for (int sh = 0; sh < 4; ++sh) {
            if (sh) {                 // shift weights one element up (insert 0 at j=0)
                unsigned n1 = (a1 << 16) | (a0 >> 16);
                unsigned n2 = (a2 << 16) | (a1 >> 16);
                unsigned n3 = (a3 << 16) | (a2 >> 16);
                a0 <<= 16; a1 = n1; a2 = n2; a3 = n3;
            }
            union { unsigned u[4]; bf16x8 v; } av;
            av.u[0] = a0; av.u[1] = a1; av.u[2] = a2; av.u[3] = a3;
            #pragma unroll
            for (int i = 0; i < 4; ++i)
                acc[i][sh] = __builtin_amdgcn_mfma_f32_16x16x32_bf16(av.v, bb[i], acc[i][sh], 0, 0, 0);
        }
    }

    // ---- epilogue: clip + float4 stores (lane covers x = 4*lx .. 4*lx+3) ----
    #pragma unroll
    for (int i = 0; i < 4; ++i) {
        float* dst = O + ((((size_t)b * 13) * 64 + ozv[i]) * 64 + oyv[i]) * 64 + 4 * lx;
        #pragma unroll
        for (int v = 0; v < 4; ++v) {
            int co = 4 * g + v;
            if (co < 13) {
                f32x4 o4 = { fminf(fmaxf(acc[i][0][v], 0.0f), 100.0f),
                             fminf(fmaxf(acc[i][1][v], 0.0f), 100.0f),
                             fminf(fmaxf(acc[i][2][v], 0.0f), 100.0f),
                             fminf(fmaxf(acc[i][3][v], 0.0f), 100.0f) };
                *(f32x4*)(dst + (size_t)co * 262144) = o4;
            }
        }
    }
}

extern "C" void kernel_launch(void* const* d_in, const int* in_sizes, int n_in,
                              void* d_out, int out_size, void* d_ws, size_t ws_size,
                              hipStream_t stream) {
    const float* X  = (const float*)d_in[0];
    const float* W  = (const float*)d_in[1];
    const float* Bv = (const float*)d_in[2];
    float* O = (float*)d_out;

    dim3 grid(64 / YB, 64 / ZB, 16);   // (8, 32, 16) = 4096 blocks
    conv13_mfma_shift<<<grid, 256, 0, stream>>>(X, W, Bv, O);
}